// Round 3
// baseline (2873.920 us; speedup 1.0000x reference)
//
#include <hip/hip_runtime.h>
#include <hip/hip_bf16.h>
#include <hip/hip_fp16.h>

// Problem constants (fixed by setup_inputs)
#define S_   2048
#define H_   2048
#define ROOM 256
#define NH   16
#define HD   128   // head_dim = 2048/16
#define TD   2048  // total_dim = 8 rooms * 256

typedef __hip_bfloat16 bf16;

// Runtime dtype codes
#define DT_F32  0
#define DT_BF16 1
#define DT_F16  2
// Operand selectors (resolved against detected mode)
#define SEL_F32   0   // always f32 (workspace intermediates)
#define SEL_IN    1   // f32-mode: f32 ; bf16-mode: bf16   (external inputs)
#define SEL_SCORE 2   // f32-mode: f32 ; bf16-mode: f16    (raw scores in attn region)
#define SEL_OUT   3   // f32-mode: f32 ; bf16-mode: bf16   (graded outputs)

__device__ __forceinline__ int resolveDT(int sel, int bf16mode) {
    if (sel == SEL_F32) return DT_F32;
    if (sel == SEL_SCORE) return bf16mode ? DT_F16 : DT_F32;
    return bf16mode ? DT_BF16 : DT_F32; // SEL_IN / SEL_OUT
}
__device__ __forceinline__ float loadF(const void* p, long i, int dt) {
    if (dt == DT_F32)  return ((const float*)p)[i];
    if (dt == DT_BF16) return __bfloat162float(((const bf16*)p)[i]);
    return __half2float(((const __half*)p)[i]);
}
__device__ __forceinline__ void storeF(void* p, long i, int dt, float v) {
    if (dt == DT_F32)       ((float*)p)[i] = v;
    else if (dt == DT_BF16) ((bf16*)p)[i] = __float2bfloat16(v);
    else                    ((__half*)p)[i] = __float2half(v);
}

// One block: detect input dtype (f32 vs bf16) + active_rooms width (i32 vs i64),
// then build the gather LUT map[n] = active_rooms[n>>8]*ROOM + (n&255).
__global__ void setup_kernel(const void* __restrict__ hidden_raw,
                             const void* __restrict__ act_raw,
                             int* __restrict__ map, int* __restrict__ flags)
{
    __shared__ int sh_mode, sh_is64;
    if (threadIdx.x == 0) {
        // dtype detect: low 16 bits of each u32 word. bf16-mode -> a real bf16
        // N(0,1) value (exponent bits 14-7 in ~[110,135]); f32-mode -> uniform
        // mantissa bits (~10% in range).
        const unsigned int* w = (const unsigned int*)hidden_raw;
        int cnt = 0;
        for (int i = 0; i < 1024; i++) {
            int e = (w[i] >> 7) & 0xFF;
            if (e >= 110 && e <= 135) cnt++;
        }
        sh_mode = (cnt > 512) ? 1 : 0;   // 1 = bf16 mode
        // active_rooms width detect: values must lie in [0,8)
        const long long* a64 = (const long long*)act_raw;
        int ok = 1;
        for (int i = 0; i < 4; i++) {    // 32 bytes, valid for either width
            long long v = a64[i];
            if (v < 0 || v >= 8) { ok = 0; break; }
        }
        sh_is64 = ok;
        flags[0] = sh_mode;
        flags[1] = sh_is64;
    }
    __syncthreads();
    const int is64 = sh_is64;
    const int*       a32 = (const int*)act_raw;
    const long long* a64 = (const long long*)act_raw;
    for (int n = threadIdx.x; n < TD; n += blockDim.x) {
        int slot = n >> 8;
        int room = is64 ? (int)a64[slot] : a32[slot];
        map[n] = room * ROOM + (n & 255);
    }
}

// Generic tiled GEMM: C = scale * A @ B(^T), f32 accumulate, runtime dtypes.
// A: [M,K] lda. TRANSB: B is [N,K] ldb, else [K,N] ldb. C: [M,N] ldc.
// GATHERB remaps B's leading row index via map[]. CAUSAL: col>row -> maskval.
// blockIdx.z adds per-head element offsets (aZ, bZ [mod-2 option], cZ);
// aBase/bBase/cBase are flat element offsets into the raw pointers.
template<bool TRANSB, bool GATHERB, bool CAUSAL>
__global__ __launch_bounds__(256)
void gemm_kernel(const void* __restrict__ A, const void* __restrict__ B, void* __restrict__ C,
                 int aSel, int bSel, int cSel,
                 int K, int lda, int ldb, int ldc,
                 long aBase, long bBase, long cBase,
                 long aZ, long bZ, int bMod2, long cZ,
                 const int* __restrict__ flags, const int* __restrict__ map,
                 float scale, float maskval)
{
    const int mode = flags[0];
    const int aDT = resolveDT(aSel, mode);
    const int bDT = resolveDT(bSel, mode);
    const int cDT = resolveDT(cSel, mode);

    const int z = blockIdx.z;
    const long aOff = aBase + (long)z * aZ;
    const long bOff = bBase + (bMod2 ? (long)(z & 1) * bZ : (long)z * bZ);
    const long cOff = cBase + (long)z * cZ;

    __shared__ float As[16][64 + 1];
    __shared__ float Bs[16][64 + 1];

    const int tid = threadIdx.x;
    const int tx = tid & 15, ty = tid >> 4;
    const int rowBase = blockIdx.y * 64;
    const int colBase = blockIdx.x * 64;

    float acc[4][4] = {};

    const int aRow  = tid >> 2;        // 0..63
    const int aCol0 = (tid & 3) * 4;   // 0,4,8,12

    for (int kt = 0; kt < K; kt += 16) {
        {   // A tile: As[k][m]
            const long base = aOff + (long)(rowBase + aRow) * lda + kt + aCol0;
            #pragma unroll
            for (int j = 0; j < 4; j++) As[aCol0 + j][aRow] = loadF(A, base + j, aDT);
        }
        if (TRANSB) {   // B[N,K] -> Bs[k][n]
            int nb = colBase + aRow;
            int grow = GATHERB ? map[nb] : nb;
            const long base = bOff + (long)grow * ldb + kt + aCol0;
            #pragma unroll
            for (int j = 0; j < 4; j++) Bs[aCol0 + j][aRow] = loadF(B, base + j, bDT);
        } else {        // B[K,N] -> Bs[k][n]
            int kk = tid >> 4;           // 0..15
            int n0 = (tid & 15) * 4;     // 0..60
            int kg = kt + kk;
            int grow = GATHERB ? map[kg] : kg;
            const long base = bOff + (long)grow * ldb + colBase + n0;
            #pragma unroll
            for (int j = 0; j < 4; j++) Bs[kk][n0 + j] = loadF(B, base + j, bDT);
        }
        __syncthreads();
        #pragma unroll
        for (int kk = 0; kk < 16; kk++) {
            float a[4], b[4];
            #pragma unroll
            for (int i = 0; i < 4; i++) a[i] = As[kk][ty * 4 + i];
            #pragma unroll
            for (int j = 0; j < 4; j++) b[j] = Bs[kk][tx * 4 + j];
            #pragma unroll
            for (int i = 0; i < 4; i++)
                #pragma unroll
                for (int j = 0; j < 4; j++)
                    acc[i][j] += a[i] * b[j];
        }
        __syncthreads();
    }

    #pragma unroll
    for (int i = 0; i < 4; i++) {
        int r = rowBase + ty * 4 + i;
        #pragma unroll
        for (int j = 0; j < 4; j++) {
            int c = colBase + tx * 4 + j;
            float v = acc[i][j] * scale;
            if (CAUSAL && c > r) v = maskval;
            storeF(C, cOff + (long)r * ldc + c, cDT, v);
        }
    }
}

// In-place row softmax over the attn region of d_out.
// Reads SEL_SCORE raw scores, writes SEL_OUT normalized weights.
__global__ __launch_bounds__(256)
void softmax_kernel(void* __restrict__ attn, long base, const int* __restrict__ flags)
{
    const int mode  = flags[0];
    const int rdDT  = resolveDT(SEL_SCORE, mode);
    const int wrDT  = resolveDT(SEL_OUT, mode);

    const int qrow = blockIdx.x;
    const int h    = blockIdx.y;
    const long row = base + ((long)h * S_ + qrow) * S_;
    const int tid  = threadIdx.x;
    const int wave = tid >> 6, lane = tid & 63;

    float vals[8];
    float m = -3.4e38f;
    #pragma unroll
    for (int i = 0; i < 8; i++) {
        int c = tid + i * 256;
        vals[i] = loadF(attn, row + c, rdDT);
        m = fmaxf(m, vals[i]);
    }
    #pragma unroll
    for (int off = 32; off > 0; off >>= 1)
        m = fmaxf(m, __shfl_down(m, off, 64));
    __shared__ float redm[4];
    if (lane == 0) redm[wave] = m;
    __syncthreads();
    if (tid == 0) redm[0] = fmaxf(fmaxf(redm[0], redm[1]), fmaxf(redm[2], redm[3]));
    __syncthreads();
    m = redm[0];

    float s = 0.f;
    #pragma unroll
    for (int i = 0; i < 8; i++) {
        vals[i] = __expf(vals[i] - m);
        s += vals[i];
    }
    #pragma unroll
    for (int off = 32; off > 0; off >>= 1)
        s += __shfl_down(s, off, 64);
    __shared__ float reds[4];
    if (lane == 0) reds[wave] = s;
    __syncthreads();
    if (tid == 0) reds[0] = reds[0] + reds[1] + reds[2] + reds[3];
    __syncthreads();
    const float inv = 1.f / reds[0];

    #pragma unroll
    for (int i = 0; i < 8; i++) {
        int c = tid + i * 256;
        storeF(attn, row + c, wrDT, vals[i] * inv);
    }
}

extern "C" void kernel_launch(void* const* d_in, const int* in_sizes, int n_in,
                              void* d_out, int out_size, void* d_ws, size_t ws_size,
                              hipStream_t stream)
{
    (void)in_sizes; (void)n_in; (void)out_size; (void)ws_size;

    const void* hidden = d_in[0];   // [1,2048,2048]   f32 or bf16 (auto)
    const void* qb     = d_in[1];   // [2048,2048]
    const void* kb     = d_in[2];   // [256,2048]
    const void* vb     = d_in[3];   // [256,2048]
    const void* ob     = d_in[4];   // [2048,2048]
    const void* act    = d_in[5];   // [8] int32 or int64 (auto)

    // d_out: o_out = elements [0, S*TD), attn = elements [S*TD, S*TD + NH*S*S)
    const long ATTN_BASE = (long)S_ * TD;

    // Workspace layout (f32): 36 MB + LUT + flags
    float* qf       = (float*)d_ws;                 // [S, TD]
    float* k_one    = qf    + (long)S_ * TD;        // [S, ROOM]
    float* v_one    = k_one + (long)S_ * ROOM;      // [S, ROOM]
    float* attn_out = v_one + (long)S_ * ROOM;      // [S, TD]
    int*   map      = (int*)(attn_out + (long)S_ * TD); // [TD]
    int*   flags    = map + TD;                     // [2]

    const dim3 blk(256);
    const float inv_sqrt_hd = 0.08838834764831845f; // 1/sqrt(128)

    setup_kernel<<<1, 256, 0, stream>>>(hidden, act, map, flags);

    // 1. qf = hidden @ gather(q_block)^T          [2048 x 2048] (K=2048)
    gemm_kernel<true, true, false>
        <<<dim3(TD / 64, S_ / 64, 1), blk, 0, stream>>>(
        hidden, qb, qf, SEL_IN, SEL_IN, SEL_F32,
        H_, H_, H_, TD, 0, 0, 0, 0, 0, 0, 0, flags, map, 1.f, 0.f);

    // 2. k_one = hidden @ k_block^T               [2048 x 256]
    gemm_kernel<true, false, false>
        <<<dim3(ROOM / 64, S_ / 64, 1), blk, 0, stream>>>(
        hidden, kb, k_one, SEL_IN, SEL_IN, SEL_F32,
        H_, H_, H_, ROOM, 0, 0, 0, 0, 0, 0, 0, flags, map, 1.f, 0.f);

    // 3. v_one = hidden @ v_block^T               [2048 x 256]
    gemm_kernel<true, false, false>
        <<<dim3(ROOM / 64, S_ / 64, 1), blk, 0, stream>>>(
        hidden, vb, v_one, SEL_IN, SEL_IN, SEL_F32,
        H_, H_, H_, ROOM, 0, 0, 0, 0, 0, 0, 0, flags, map, 1.f, 0.f);

    // 4. raw scores (causal-masked) into attn region, per head (grid.z)
    //    A = qf[:, z*128:], B = k_one[:, (z&1)*128:], scale 1/sqrt(128)
    gemm_kernel<true, false, true>
        <<<dim3(S_ / 64, S_ / 64, NH), blk, 0, stream>>>(
        qf, k_one, d_out, SEL_F32, SEL_F32, SEL_SCORE,
        HD, TD, ROOM, S_, 0, 0, ATTN_BASE,
        (long)HD, (long)HD, 1, (long)S_ * S_, flags, map, inv_sqrt_hd, -1e4f);

    // 5. in-place softmax: raw scores -> weights (graded output 1)
    softmax_kernel<<<dim3(S_, NH), blk, 0, stream>>>(d_out, ATTN_BASE, flags);

    // 6. attn_out[:, z*128:] = P_z @ v_one[:, (z&1)*128:]   (K=2048, N=128)
    gemm_kernel<false, false, false>
        <<<dim3(HD / 64, S_ / 64, NH), blk, 0, stream>>>(
        d_out, v_one, attn_out, SEL_OUT, SEL_F32, SEL_F32,
        S_, S_, ROOM, TD, ATTN_BASE, 0, 0,
        (long)S_ * S_, (long)HD, 1, (long)HD, flags, map, 1.f, 0.f);

    // 7. o_out = attn_out @ gather(o_block)       [2048 x 2048] (K=2048)
    gemm_kernel<false, true, false>
        <<<dim3(H_ / 64, S_ / 64, 1), blk, 0, stream>>>(
        attn_out, ob, d_out, SEL_F32, SEL_IN, SEL_OUT,
        TD, TD, H_, H_, 0, 0, 0, 0, 0, 0, 0, flags, map, 1.f, 0.f);
}